// Round 1
// baseline (12265.440 us; speedup 1.0000x reference)
//
#include <hip/hip_runtime.h>
#include <math.h>

#define LQ 2048
#define DMODEL 1024
#define NH 16
#define DH 64
#define LR 4095  // 2*LQ-1

// ---------------------------------------------------------------------------
// GEMM: C[M,N] = A[M,K] * B[N,K]^T   (K = N = 1024)
// BM=BN=64, BK=16, 256 threads, 4x4 micro-tile per thread.
// RPE=true: A is the virtual sinusoidal matrix r[t, :], computed on the fly.
// ---------------------------------------------------------------------------
template<bool RPE>
__global__ __launch_bounds__(256)
void gemm_nt_f32(const float* __restrict__ A, const float* __restrict__ B,
                 float* __restrict__ C, int M) {
    const int K = DMODEL, N = DMODEL;
    __shared__ float As[64][17];
    __shared__ float Bs[64][17];
    const int m0 = blockIdx.x * 64, n0 = blockIdx.y * 64;
    const int t  = threadIdx.x;
    const int tx = t & 15, ty = t >> 4;
    float acc[4][4] = {};

    for (int k0 = 0; k0 < K; k0 += 16) {
        // A tile: 64x16 = 1024 elems, 4 per thread
        #pragma unroll
        for (int l = 0; l < 4; ++l) {
            int e = l * 256 + t;
            int r = e >> 4, c = e & 15;
            int gm = m0 + r, gk = k0 + c;
            float val;
            if (RPE) {
                if (gm < M) {
                    int c2 = gk >> 1;
                    // inv_freq = 10000^(-(c2)/512) = exp(-c2 * ln(1e4)/512)
                    float invf = expf(-(float)c2 * (9.210340371976184f / 512.0f));
                    float ang  = (float)(gm - (LQ - 1)) * invf;
                    val = (gk & 1) ? cosf(ang) : sinf(ang);
                } else val = 0.f;
            } else {
                val = (gm < M) ? A[(size_t)gm * K + gk] : 0.f;
            }
            As[r][c] = val;
        }
        // B tile: rows n0..n0+63 always in range (N=1024)
        #pragma unroll
        for (int l = 0; l < 4; ++l) {
            int e = l * 256 + t;
            int r = e >> 4, c = e & 15;
            Bs[r][c] = B[(size_t)(n0 + r) * K + k0 + c];
        }
        __syncthreads();
        #pragma unroll
        for (int kk = 0; kk < 16; ++kk) {
            float a[4], b[4];
            #pragma unroll
            for (int x = 0; x < 4; ++x) { a[x] = As[ty * 4 + x][kk]; b[x] = Bs[tx * 4 + x][kk]; }
            #pragma unroll
            for (int x = 0; x < 4; ++x)
                #pragma unroll
                for (int y = 0; y < 4; ++y)
                    acc[x][y] += a[x] * b[y];
        }
        __syncthreads();
    }
    #pragma unroll
    for (int x = 0; x < 4; ++x) {
        int gm = m0 + ty * 4 + x;
        if (gm < M) {
            #pragma unroll
            for (int y = 0; y < 4; ++y)
                C[(size_t)gm * N + n0 + tx * 4 + y] = acc[x][y];
        }
    }
}

// ---------------------------------------------------------------------------
// Fused rel-attention: per block = (head h, 32 query rows), flash-style loop
// over 32-col j tiles with online softmax.
// rel_shift resolved as:
//   j <= i   : BD = (q_i+vb) . rp[j-i+4094]
//   j == i+1 : BD = 0
//   j >= i+2 : BD = (q_{i+1}+vb) . rp[j-i-2]
// Both rp bands staged per j-tile; band row index = jl - rr + 31 for both.
// ---------------------------------------------------------------------------
__global__ __launch_bounds__(256)
void attn_kernel(const float* __restrict__ q, const float* __restrict__ k,
                 const float* __restrict__ v, const float* __restrict__ rp,
                 const float* __restrict__ ub, const float* __restrict__ vb,
                 float* __restrict__ out) {
    const int h   = blockIdx.y;
    const int i0  = blockIdx.x * 32;
    const int t   = threadIdx.x;
    const int col0 = h * DH;

    __shared__ float qu_s[32][65];
    __shared__ float qv_s[33][65];
    __shared__ float k_s [32][65];
    __shared__ float v_s [32][65];
    __shared__ float blo [64][65];
    __shared__ float bup [64][65];
    __shared__ float S   [32][33];

    // stage qu (q+u_bias) and qv (q+v_bias): 2048 elems, 8 per thread
    #pragma unroll
    for (int l = 0; l < 8; ++l) {
        int e = l * 256 + t;
        int r = e >> 6, d = e & 63;
        float qval = q[(size_t)(i0 + r) * DMODEL + col0 + d];
        qu_s[r][d] = qval + ub[col0 + d];
        qv_s[r][d] = qval + vb[col0 + d];
    }
    if (t < 64) {  // extra qv row i0+32 (used by j >= i+2 for the last row)
        int gi = i0 + 32;
        float qval = (gi < LQ) ? q[(size_t)gi * DMODEL + col0 + t] : 0.f;
        qv_s[32][t] = qval + vb[col0 + t];
    }

    const int rr = t >> 3;   // query row in tile, 0..31
    const int s8 = t & 7;    // 0..7: j-stripe and d-slice owner
    const int d0 = s8 * 8;
    float m_run = -1e30f, l_run = 0.f;
    float acc[8] = {};

    for (int j0 = 0; j0 < LQ; j0 += 32) {
        __syncthreads();  // covers initial qu/qv staging and prior-iter reads
        // stage k,v tiles
        #pragma unroll
        for (int l = 0; l < 8; ++l) {
            int e = l * 256 + t;
            int r = e >> 6, d = e & 63;
            k_s[r][d] = k[(size_t)(j0 + r) * DMODEL + col0 + d];
            v_s[r][d] = v[(size_t)(j0 + r) * DMODEL + col0 + d];
        }
        // stage rp bands (64 rows each), zero-fill out-of-range (never used)
        const int tlo0 = (j0 - i0) + 4063;
        const int tup0 = (j0 - i0) - 33;
        #pragma unroll
        for (int l = 0; l < 16; ++l) {
            int e = l * 256 + t;
            int r = e >> 6, d = e & 63;
            int tl = tlo0 + r;
            blo[r][d] = (tl >= 0 && tl < LR) ? rp[(size_t)tl * DMODEL + col0 + d] : 0.f;
            int tu = tup0 + r;
            bup[r][d] = (tu >= 0 && tu < LR) ? rp[(size_t)tu * DMODEL + col0 + d] : 0.f;
        }
        __syncthreads();

        // scores: thread handles (rr, jl = s8 + 8*jj), jj = 0..3
        const int gi = i0 + rr;
        float sc[4];
        #pragma unroll
        for (int jj = 0; jj < 4; ++jj) {
            int jl = s8 + jj * 8;
            int gj = j0 + jl;
            float ac = 0.f;
            #pragma unroll
            for (int d = 0; d < DH; ++d) ac += qu_s[rr][d] * k_s[jl][d];
            float bd = 0.f;
            int bi = jl - rr + 31;
            if (gj <= gi) {
                #pragma unroll
                for (int d = 0; d < DH; ++d) bd += qv_s[rr][d] * blo[bi][d];
            } else if (gj >= gi + 2) {
                #pragma unroll
                for (int d = 0; d < DH; ++d) bd += qv_s[rr + 1][d] * bup[bi][d];
            }
            sc[jj] = (ac + bd) * 0.125f;
        }

        // online softmax (8-lane row groups)
        float mx = fmaxf(fmaxf(sc[0], sc[1]), fmaxf(sc[2], sc[3]));
        #pragma unroll
        for (int o = 1; o < 8; o <<= 1) mx = fmaxf(mx, __shfl_xor(mx, o, 64));
        float m_new = fmaxf(m_run, mx);
        float fac = __expf(m_run - m_new);
        float psum = 0.f;
        #pragma unroll
        for (int jj = 0; jj < 4; ++jj) {
            float p = __expf(sc[jj] - m_new);
            S[rr][s8 + jj * 8] = p;
            psum += p;
        }
        #pragma unroll
        for (int o = 1; o < 8; o <<= 1) psum += __shfl_xor(psum, o, 64);
        l_run = l_run * fac + psum;
        m_run = m_new;
        #pragma unroll
        for (int dd = 0; dd < 8; ++dd) acc[dd] *= fac;
        __syncthreads();

        // PV accumulate: this thread owns d-slice [d0, d0+8)
        for (int j2 = 0; j2 < 32; ++j2) {
            float p = S[rr][j2];
            #pragma unroll
            for (int dd = 0; dd < 8; ++dd) acc[dd] += p * v_s[j2][d0 + dd];
        }
    }

    const float inv_l = 1.f / l_run;
    const int gi = i0 + rr;
    #pragma unroll
    for (int dd = 0; dd < 8; ++dd)
        out[(size_t)gi * DMODEL + col0 + d0 + dd] = acc[dd] * inv_l;
}

// ---------------------------------------------------------------------------
extern "C" void kernel_launch(void* const* d_in, const int* in_sizes, int n_in,
                              void* d_out, int out_size, void* d_ws, size_t ws_size,
                              hipStream_t stream) {
    const float* w  = (const float*)d_in[0];
    const float* Wq = (const float*)d_in[1];
    const float* Wk = (const float*)d_in[2];
    const float* Wv = (const float*)d_in[3];
    const float* Wr = (const float*)d_in[4];
    const float* ub = (const float*)d_in[5];
    const float* vb = (const float*)d_in[6];
    float* out = (float*)d_out;
    float* ws  = (float*)d_ws;

    float* q  = ws;
    float* kk = ws + (size_t)1 * LQ * DMODEL;
    float* vv = ws + (size_t)2 * LQ * DMODEL;
    float* rp = ws + (size_t)3 * LQ * DMODEL;   // LR*DMODEL floats

    dim3 blk(256);
    dim3 g1(LQ / 64, DMODEL / 64);
    hipLaunchKernelGGL((gemm_nt_f32<false>), g1, blk, 0, stream, w, Wq, q, LQ);
    hipLaunchKernelGGL((gemm_nt_f32<false>), g1, blk, 0, stream, w, Wk, kk, LQ);
    hipLaunchKernelGGL((gemm_nt_f32<false>), g1, blk, 0, stream, w, Wv, vv, LQ);
    dim3 g2((LR + 63) / 64, DMODEL / 64);
    hipLaunchKernelGGL((gemm_nt_f32<true>), g2, blk, 0, stream, nullptr, Wr, rp, LR);
    dim3 g3(LQ / 32, NH);
    hipLaunchKernelGGL(attn_kernel, g3, blk, 0, stream, q, kk, vv, rp, ub, vb, out);
}

// Round 2
// 389.521 us; speedup vs baseline: 31.4885x; 31.4885x over previous
//
#include <hip/hip_runtime.h>
#include <math.h>

#define LQ 2048
#define DM 1024
#define NH 16
#define DH 64
#define LR 4095  // 2*LQ-1

typedef __attribute__((ext_vector_type(4))) float f4v;
typedef __attribute__((ext_vector_type(8))) short s8v;
typedef __attribute__((ext_vector_type(4))) unsigned short us4;

__device__ __forceinline__ unsigned short f2bf(float x) {
    unsigned int u = __float_as_uint(x);
    return (unsigned short)((u + 0x7FFFu + ((u >> 16) & 1u)) >> 16);
}
__device__ __forceinline__ float bf2f(unsigned short s) {
    return __uint_as_float(((unsigned int)s) << 16);
}

// ---------------------------------------------------------------------------
// sinusoidal r matrix [LR x DM] in bf16
// ---------------------------------------------------------------------------
__global__ __launch_bounds__(256)
void r_kernel(unsigned short* __restrict__ r) {
    int idx = blockIdx.x * 256 + threadIdx.x;   // exactly LR*DM threads
    int gm = idx >> 10, gk = idx & 1023;
    int c2 = gk >> 1;
    float invf = expf(-(float)c2 * (9.210340371976184f / 512.0f));
    float ang = (float)(gm - (LQ - 1)) * invf;
    float v = (gk & 1) ? cosf(ang) : sinf(ang);
    r[idx] = f2bf(v);
}

// ---------------------------------------------------------------------------
// C[M,N] = A[M,K] @ B[N,K]^T, bf16 MFMA, f32->bf16 cast on the fly.
// BM=BN=64, BK=64, 256 threads (4 waves), each wave a 32x32 quadrant.
// ---------------------------------------------------------------------------
template<typename TA>
__global__ __launch_bounds__(256)
void gemm_mfma(const TA* __restrict__ A, const float* __restrict__ B,
               unsigned short* __restrict__ C, int M) {
    __shared__ unsigned short As[64][72];
    __shared__ unsigned short Bs[64][72];
    const int m0 = blockIdx.x * 64, n0 = blockIdx.y * 64;
    const int t = threadIdx.x;
    const int w = t >> 6;
    const int lan16 = t & 15, lgrp = (t & 63) >> 4;
    const int wm = (w >> 1) * 32, wn = (w & 1) * 32;
    f4v acc[2][2] = {};

    for (int k0 = 0; k0 < DM; k0 += 64) {
        #pragma unroll
        for (int l = 0; l < 4; ++l) {
            int idx = l * 256 + t;
            int row = idx >> 4, c4 = (idx & 15) * 4;
            int gm = m0 + row;
            us4 pa;
            if (gm < M) {
                if constexpr (sizeof(TA) == 4) {
                    const float* ap = (const float*)A + (size_t)gm * DM + k0 + c4;
                    pa = (us4){f2bf(ap[0]), f2bf(ap[1]), f2bf(ap[2]), f2bf(ap[3])};
                } else {
                    pa = *(const us4*)((const unsigned short*)A + (size_t)gm * DM + k0 + c4);
                }
            } else pa = (us4){0, 0, 0, 0};
            *(us4*)&As[row][c4] = pa;
            const float* bp = B + (size_t)(n0 + row) * DM + k0 + c4;
            *(us4*)&Bs[row][c4] = (us4){f2bf(bp[0]), f2bf(bp[1]), f2bf(bp[2]), f2bf(bp[3])};
        }
        __syncthreads();
        #pragma unroll
        for (int kk = 0; kk < 2; ++kk) {
            s8v aF[2], bF[2];
            #pragma unroll
            for (int i = 0; i < 2; ++i) {
                aF[i] = *(const s8v*)&As[wm + i * 16 + lan16][kk * 32 + lgrp * 8];
                bF[i] = *(const s8v*)&Bs[wn + i * 16 + lan16][kk * 32 + lgrp * 8];
            }
            #pragma unroll
            for (int i = 0; i < 2; ++i)
                #pragma unroll
                for (int j = 0; j < 2; ++j)
                    acc[i][j] = __builtin_amdgcn_mfma_f32_16x16x32_bf16(aF[i], bF[j], acc[i][j], 0, 0, 0);
        }
        __syncthreads();
    }
    #pragma unroll
    for (int i = 0; i < 2; ++i)
        #pragma unroll
        for (int j = 0; j < 2; ++j)
            #pragma unroll
            for (int rg = 0; rg < 4; ++rg) {
                int row = m0 + wm + i * 16 + lgrp * 4 + rg;
                int col = n0 + wn + j * 16 + lan16;
                if (row < M) C[(size_t)row * DM + col] = f2bf(acc[i][j][rg]);
            }
}

// ---------------------------------------------------------------------------
// Fused rel-attention, MFMA. Block = (head, 64 q rows). j-tiles of 64.
// BD via 128-wide band GEMM + bijective register scatter:
//   lower (gj<=gi):   rp row = (gj-gi)+4094, band base = j0-i0+4031, A = qv[rr]
//   upper (gj>=gi+2): rp row = (gj-gi)-2,    band base = j0-i0-65,   A = qv[rr+1]
//   jl = bcol + rr - 63
// ---------------------------------------------------------------------------
__global__ __launch_bounds__(256)
void attn_mfma(const unsigned short* __restrict__ q, const unsigned short* __restrict__ kw,
               const unsigned short* __restrict__ vw, const unsigned short* __restrict__ rp,
               const float* __restrict__ ub, const float* __restrict__ vb,
               float* __restrict__ out) {
    __shared__ unsigned short Ks[64][72];
    __shared__ unsigned short Vt[64][72];
    __shared__ unsigned short band[128][72];
    __shared__ float S[64][68];
    __shared__ unsigned short P[64][72];
    __shared__ float facs[64];

    const int h = blockIdx.y, i0 = blockIdx.x * 64;
    const int col0 = h * DH;
    const int t = threadIdx.x;
    const int w = t >> 6;
    const int lan16 = t & 15, lgrp = (t & 63) >> 4;
    const int wstrip = w * 16;
    const float L2E = 1.4426950408889634f;

    s8v quF[2], qvlF[2], qvsF[2];
    // stage QU = q + ub into band rows 0..63, preload frags
    #pragma unroll
    for (int l = 0; l < 4; ++l) {
        int idx = l * 256 + t;
        int row = idx >> 4, c4 = (idx & 15) * 4;
        us4 qv = *(const us4*)(q + (size_t)(i0 + row) * DM + col0 + c4);
        us4 o;
        #pragma unroll
        for (int i = 0; i < 4; ++i) o[i] = f2bf(bf2f(qv[i]) + ub[col0 + c4 + i]);
        *(us4*)&band[row][c4] = o;
    }
    __syncthreads();
    quF[0] = *(const s8v*)&band[wstrip + lan16][lgrp * 8];
    quF[1] = *(const s8v*)&band[wstrip + lan16][32 + lgrp * 8];
    __syncthreads();
    // stage QV rows 0..64 (row 64 = next tile's first row, zero past end)
    #pragma unroll
    for (int l = 0; l < 5; ++l) {
        int idx = l * 256 + t;
        if (idx < 65 * 16) {
            int row = idx >> 4, c4 = (idx & 15) * 4;
            int gi = i0 + row;
            us4 o = (us4){0, 0, 0, 0};
            if (gi < LQ) {
                us4 qv = *(const us4*)(q + (size_t)gi * DM + col0 + c4);
                #pragma unroll
                for (int i = 0; i < 4; ++i) o[i] = f2bf(bf2f(qv[i]) + vb[col0 + c4 + i]);
            }
            *(us4*)&band[row][c4] = o;
        }
    }
    __syncthreads();
    qvlF[0] = *(const s8v*)&band[wstrip + lan16][lgrp * 8];
    qvlF[1] = *(const s8v*)&band[wstrip + lan16][32 + lgrp * 8];
    qvsF[0] = *(const s8v*)&band[wstrip + 1 + lan16][lgrp * 8];
    qvsF[1] = *(const s8v*)&band[wstrip + 1 + lan16][32 + lgrp * 8];
    __syncthreads();

    f4v accO[4] = {};
    float m_run = -1e30f, l_run = 0.f;
    const int sr = t >> 2;           // softmax row (strip-local: wave w owns rows 16w..)
    const int sc0 = (t & 3) * 16;

    for (int j0 = 0; j0 < LQ; j0 += 64) {
        const bool needLo = (j0 <= i0), needUp = (j0 >= i0);
        // stage K, V^T
        #pragma unroll
        for (int l = 0; l < 4; ++l) {
            int idx = l * 256 + t;
            int row = idx >> 4, c4 = (idx & 15) * 4;
            *(us4*)&Ks[row][c4] = *(const us4*)(kw + (size_t)(j0 + row) * DM + col0 + c4);
            us4 vv = *(const us4*)(vw + (size_t)(j0 + row) * DM + col0 + c4);
            #pragma unroll
            for (int i = 0; i < 4; ++i) Vt[c4 + i][row] = vv[i];
        }
        // stage first band
        {
            int base = needLo ? (j0 - i0 + 4031) : (j0 - i0 - 65);
            #pragma unroll
            for (int l = 0; l < 8; ++l) {
                int idx = l * 256 + t;
                int row = idx >> 4, c4 = (idx & 15) * 4;
                int trow = base + row;
                us4 o = (us4){0, 0, 0, 0};
                if (trow >= 0 && trow < LR)
                    o = *(const us4*)(rp + (size_t)trow * DM + col0 + c4);
                *(us4*)&band[row][c4] = o;
            }
        }
        __syncthreads();

        // AC = QU @ K^T -> S
        {
            f4v acF[4] = {};
            #pragma unroll
            for (int nf = 0; nf < 4; ++nf)
                #pragma unroll
                for (int kk = 0; kk < 2; ++kk) {
                    s8v bF = *(const s8v*)&Ks[nf * 16 + lan16][kk * 32 + lgrp * 8];
                    acF[nf] = __builtin_amdgcn_mfma_f32_16x16x32_bf16(quF[kk], bF, acF[nf], 0, 0, 0);
                }
            #pragma unroll
            for (int nf = 0; nf < 4; ++nf)
                #pragma unroll
                for (int rg = 0; rg < 4; ++rg)
                    S[wstrip + lgrp * 4 + rg][nf * 16 + lan16] = acF[nf][rg];
        }
        // BD band pass(es): G = QV @ band^T, scatter diagonals into S
        auto gpass = [&](bool isLo, const s8v* qf) {
            #pragma unroll
            for (int nf = 0; nf < 8; ++nf) {
                f4v g = {};
                #pragma unroll
                for (int kk = 0; kk < 2; ++kk) {
                    s8v bF = *(const s8v*)&band[nf * 16 + lan16][kk * 32 + lgrp * 8];
                    g = __builtin_amdgcn_mfma_f32_16x16x32_bf16(qf[kk], bF, g, 0, 0, 0);
                }
                #pragma unroll
                for (int rg = 0; rg < 4; ++rg) {
                    int rr = wstrip + lgrp * 4 + rg;
                    int jl = nf * 16 + lan16 + rr - 63;
                    if (jl >= 0 && jl < 64) {
                        int gj = j0 + jl, gi = i0 + rr;
                        bool ok = isLo ? (gj <= gi) : (gj >= gi + 2);
                        if (ok) S[rr][jl] += g[rg];
                    }
                }
            }
        };
        if (needLo) gpass(true, qvlF);
        else        gpass(false, qvsF);
        if (needLo && needUp) {  // diagonal tile: second band
            __syncthreads();
            int base = j0 - i0 - 65;
            #pragma unroll
            for (int l = 0; l < 8; ++l) {
                int idx = l * 256 + t;
                int row = idx >> 4, c4 = (idx & 15) * 4;
                int trow = base + row;
                us4 o = (us4){0, 0, 0, 0};
                if (trow >= 0 && trow < LR)
                    o = *(const us4*)(rp + (size_t)trow * DM + col0 + c4);
                *(us4*)&band[row][c4] = o;
            }
            __syncthreads();
            gpass(false, qvsF);
        }

        // online softmax (strip-local rows)
        {
            float sv[16]; float mx = -1e30f;
            #pragma unroll
            for (int c = 0; c < 16; ++c) { sv[c] = S[sr][sc0 + c] * 0.125f; mx = fmaxf(mx, sv[c]); }
            mx = fmaxf(mx, __shfl_xor(mx, 1, 64));
            mx = fmaxf(mx, __shfl_xor(mx, 2, 64));
            float mnew = fmaxf(m_run, mx);
            float fac = exp2f((m_run - mnew) * L2E);
            float ps = 0.f;
            #pragma unroll
            for (int cb = 0; cb < 4; ++cb) {
                us4 o;
                #pragma unroll
                for (int i = 0; i < 4; ++i) {
                    float p = exp2f((sv[cb * 4 + i] - mnew) * L2E);
                    ps += p; o[i] = f2bf(p);
                }
                *(us4*)&P[sr][sc0 + cb * 4] = o;
            }
            ps += __shfl_xor(ps, 1, 64);
            ps += __shfl_xor(ps, 2, 64);
            l_run = l_run * fac + ps;
            m_run = mnew;
            if ((t & 3) == 0) facs[sr] = fac;
        }
        // PV: rescale acc, out += P @ V
        {
            float fr[4];
            #pragma unroll
            for (int rg = 0; rg < 4; ++rg) fr[rg] = facs[wstrip + lgrp * 4 + rg];
            #pragma unroll
            for (int nf = 0; nf < 4; ++nf)
                #pragma unroll
                for (int rg = 0; rg < 4; ++rg) accO[nf][rg] *= fr[rg];
            s8v pF[2];
            pF[0] = *(const s8v*)&P[wstrip + lan16][lgrp * 8];
            pF[1] = *(const s8v*)&P[wstrip + lan16][32 + lgrp * 8];
            #pragma unroll
            for (int nf = 0; nf < 4; ++nf)
                #pragma unroll
                for (int kk = 0; kk < 2; ++kk) {
                    s8v vF = *(const s8v*)&Vt[nf * 16 + lan16][kk * 32 + lgrp * 8];
                    accO[nf] = __builtin_amdgcn_mfma_f32_16x16x32_bf16(pF[kk], vF, accO[nf], 0, 0, 0);
                }
        }
        __syncthreads();
    }

    // epilogue: normalize and store
    if ((t & 3) == 0) facs[sr] = 1.f / l_run;
    __syncthreads();
    float lr[4];
    #pragma unroll
    for (int rg = 0; rg < 4; ++rg) lr[rg] = facs[wstrip + lgrp * 4 + rg];
    #pragma unroll
    for (int nf = 0; nf < 4; ++nf)
        #pragma unroll
        for (int rg = 0; rg < 4; ++rg)
            out[(size_t)(i0 + wstrip + lgrp * 4 + rg) * DM + col0 + nf * 16 + lan16] = accO[nf][rg] * lr[rg];
}

// ---------------------------------------------------------------------------
extern "C" void kernel_launch(void* const* d_in, const int* in_sizes, int n_in,
                              void* d_out, int out_size, void* d_ws, size_t ws_size,
                              hipStream_t stream) {
    const float* w  = (const float*)d_in[0];
    const float* Wq = (const float*)d_in[1];
    const float* Wk = (const float*)d_in[2];
    const float* Wv = (const float*)d_in[3];
    const float* Wr = (const float*)d_in[4];
    const float* ub = (const float*)d_in[5];
    const float* vb = (const float*)d_in[6];
    float* out = (float*)d_out;

    unsigned short* q  = (unsigned short*)d_ws;
    unsigned short* kk = q  + (size_t)LQ * DM;
    unsigned short* vv = kk + (size_t)LQ * DM;
    unsigned short* rp = vv + (size_t)LQ * DM;
    unsigned short* r  = rp + (size_t)LR * DM;

    dim3 blk(256);
    hipLaunchKernelGGL(r_kernel, dim3(LR * 4), blk, 0, stream, r);
    hipLaunchKernelGGL((gemm_mfma<float>), dim3(32, 16), blk, 0, stream, w, Wq, q, LQ);
    hipLaunchKernelGGL((gemm_mfma<float>), dim3(32, 16), blk, 0, stream, w, Wk, kk, LQ);
    hipLaunchKernelGGL((gemm_mfma<float>), dim3(32, 16), blk, 0, stream, w, Wv, vv, LQ);
    hipLaunchKernelGGL((gemm_mfma<unsigned short>), dim3(64, 16), blk, 0, stream, r, Wr, rp, LR);
    hipLaunchKernelGGL(attn_mfma, dim3(32, 16), blk, 0, stream, q, kk, vv, rp, ub, vb, out);
}

// Round 3
// 223.185 us; speedup vs baseline: 54.9564x; 1.7453x over previous
//
#include <hip/hip_runtime.h>
#include <math.h>

#define LQ 2048
#define DM 1024
#define NH 16
#define DH 64
#define LR 4095  // 2*LQ-1

typedef __attribute__((ext_vector_type(4))) float f4v;
typedef __attribute__((ext_vector_type(8))) short s8v;
typedef __attribute__((ext_vector_type(2))) unsigned short us2;
typedef __attribute__((ext_vector_type(8))) unsigned short us8;

__device__ __forceinline__ unsigned short f2bf(float x) {
    unsigned int u = __float_as_uint(x);
    return (unsigned short)((u + 0x7FFFu + ((u >> 16) & 1u)) >> 16);
}
__device__ __forceinline__ float bf2f(unsigned short s) {
    return __uint_as_float(((unsigned int)s) << 16);
}

// ---------------------------------------------------------------------------
// cast f32 inputs -> one contiguous bf16 region: [w(2M) | Wq | Wk | Wv | Wr]
// ---------------------------------------------------------------------------
__global__ __launch_bounds__(256)
void cast_all(const float* __restrict__ w, const float* __restrict__ Wq,
              const float* __restrict__ Wk, const float* __restrict__ Wv,
              const float* __restrict__ Wr, unsigned short* __restrict__ dst) {
    size_t e0 = ((size_t)blockIdx.x * 256 + threadIdx.x) * 8;
    const float* src;
    if (e0 < (size_t)LQ * DM) src = w + e0;
    else {
        size_t ro = e0 - (size_t)LQ * DM;
        int wi = (int)(ro >> 20);
        size_t off = ro & 1048575;
        src = (wi == 0 ? Wq : wi == 1 ? Wk : wi == 2 ? Wv : Wr) + off;
    }
    f4v a = *(const f4v*)src;
    f4v b = *(const f4v*)(src + 4);
    us8 o;
    o[0]=f2bf(a[0]); o[1]=f2bf(a[1]); o[2]=f2bf(a[2]); o[3]=f2bf(a[3]);
    o[4]=f2bf(b[0]); o[5]=f2bf(b[1]); o[6]=f2bf(b[2]); o[7]=f2bf(b[3]);
    *(us8*)(dst + e0) = o;
}

// ---------------------------------------------------------------------------
// sinusoidal r [LR x DM] bf16; one thread per (pos, freq) pair
// ---------------------------------------------------------------------------
__global__ __launch_bounds__(256)
void r_kernel(unsigned short* __restrict__ r) {
    int tg = blockIdx.x * 256 + threadIdx.x;   // 4095*512 threads exactly
    int gm = tg >> 9, c2 = tg & 511;
    float invf = expf(-(float)c2 * (9.210340371976184f / 512.0f));
    float ang = (float)(gm - (LQ - 1)) * invf;
    us2 o; o[0] = f2bf(sinf(ang)); o[1] = f2bf(cosf(ang));
    *(us2*)&r[(size_t)gm * DM + c2 * 2] = o;
}

// ---------------------------------------------------------------------------
// C[M,N]=A@B^T bf16, 128x128 tile, BK=64, 4 waves (64x64 quadrant, 4x4 frags)
// gridDim.y = 8 per matrix; mat = blockIdx.y>>3 selects (b,c) pointer pair.
// ---------------------------------------------------------------------------
__global__ __launch_bounds__(256)
void proj_gemm(const unsigned short* __restrict__ A,
               const unsigned short* __restrict__ b0, const unsigned short* __restrict__ b1,
               const unsigned short* __restrict__ b2,
               unsigned short* __restrict__ c0, unsigned short* __restrict__ c1,
               unsigned short* __restrict__ c2_, int M) {
    __shared__ unsigned short As[128][72];
    __shared__ unsigned short Bs[128][72];
    const int mat = blockIdx.y >> 3;
    const int m0 = blockIdx.x * 128, n0 = (blockIdx.y & 7) * 128;
    const unsigned short* B = mat == 0 ? b0 : mat == 1 ? b1 : b2;
    unsigned short* C = mat == 0 ? c0 : mat == 1 ? c1 : c2_;
    const int t = threadIdx.x;
    const int w = t >> 6, lan16 = t & 15, lgrp = (t & 63) >> 4;
    const int wm = (w >> 1) * 64, wn = (w & 1) * 64;
    f4v acc[4][4] = {};
    for (int k0 = 0; k0 < DM; k0 += 64) {
        #pragma unroll
        for (int l = 0; l < 4; ++l) {
            int slot = l * 256 + t;
            int row = slot >> 3, col8 = (slot & 7) * 8;
            int gm = m0 + row;
            us8 av = (us8){0,0,0,0,0,0,0,0};
            if (gm < M) av = *(const us8*)(A + (size_t)gm * DM + k0 + col8);
            *(us8*)&As[row][col8] = av;
            *(us8*)&Bs[row][col8] = *(const us8*)(B + (size_t)(n0 + row) * DM + k0 + col8);
        }
        __syncthreads();
        #pragma unroll
        for (int kk = 0; kk < 2; ++kk) {
            s8v aF[4], bF[4];
            #pragma unroll
            for (int i = 0; i < 4; ++i) {
                aF[i] = *(const s8v*)&As[wm + i * 16 + lan16][kk * 32 + lgrp * 8];
                bF[i] = *(const s8v*)&Bs[wn + i * 16 + lan16][kk * 32 + lgrp * 8];
            }
            #pragma unroll
            for (int i = 0; i < 4; ++i)
                #pragma unroll
                for (int j = 0; j < 4; ++j)
                    acc[i][j] = __builtin_amdgcn_mfma_f32_16x16x32_bf16(aF[i], bF[j], acc[i][j], 0, 0, 0);
        }
        __syncthreads();
    }
    #pragma unroll
    for (int i = 0; i < 4; ++i)
        #pragma unroll
        for (int j = 0; j < 4; ++j)
            #pragma unroll
            for (int rg = 0; rg < 4; ++rg) {
                int row = m0 + wm + i * 16 + lgrp * 4 + rg;
                if (row < M)
                    C[(size_t)row * DM + n0 + wn + j * 16 + lan16] = f2bf(acc[i][j][rg]);
            }
}

// ---------------------------------------------------------------------------
// Fused rel-attention. Block = (head, 64 q rows), j-tiles of 64.
// Fragment-register softmax; write-once BD scatter with per-wave 5-col window.
// ---------------------------------------------------------------------------
__global__ __launch_bounds__(256)
void attn_mfma(const unsigned short* __restrict__ q, const unsigned short* __restrict__ kw,
               const unsigned short* __restrict__ vw, const unsigned short* __restrict__ rp,
               const float* __restrict__ ub, const float* __restrict__ vb,
               float* __restrict__ out) {
    __shared__ unsigned short Ks[64][72];
    __shared__ unsigned short Vt[64][72];
    __shared__ unsigned short band[128][72];
    __shared__ float BD[64][66];
    __shared__ unsigned short P[64][72];

    const int h = blockIdx.y, i0 = blockIdx.x * 64;
    const int col0 = h * DH;
    const int t = threadIdx.x;
    const int w = t >> 6, lan16 = t & 15, lgrp = (t & 63) >> 4;
    const int W = w * 16;
    const float L2E = 1.4426950408889634f;

    s8v quF[2], qvlF[2], qvsF[2];
    // stage QU = q + ub into band rows 0..63, preload frags
    #pragma unroll
    for (int l = 0; l < 2; ++l) {
        int slot = l * 256 + t;
        int row = slot >> 3, col8 = (slot & 7) * 8;
        us8 qv = *(const us8*)(q + (size_t)(i0 + row) * DM + col0 + col8);
        us8 o;
        #pragma unroll
        for (int i = 0; i < 8; ++i) o[i] = f2bf(bf2f(qv[i]) + ub[col0 + col8 + i]);
        *(us8*)&band[row][col8] = o;
    }
    __syncthreads();
    quF[0] = *(const s8v*)&band[W + lan16][lgrp * 8];
    quF[1] = *(const s8v*)&band[W + lan16][32 + lgrp * 8];
    __syncthreads();
    // stage QV rows 0..64 (row 64 = next tile's first row; zero past end)
    #pragma unroll
    for (int l = 0; l < 3; ++l) {
        int slot = l * 256 + t;
        if (slot < 65 * 8) {
            int row = slot >> 3, col8 = (slot & 7) * 8;
            int gi = i0 + row;
            us8 o = (us8){0,0,0,0,0,0,0,0};
            if (gi < LQ) {
                us8 qv = *(const us8*)(q + (size_t)gi * DM + col0 + col8);
                #pragma unroll
                for (int i = 0; i < 8; ++i) o[i] = f2bf(bf2f(qv[i]) + vb[col0 + col8 + i]);
            }
            *(us8*)&band[row][col8] = o;
        }
    }
    __syncthreads();
    qvlF[0] = *(const s8v*)&band[W + lan16][lgrp * 8];
    qvlF[1] = *(const s8v*)&band[W + lan16][32 + lgrp * 8];
    qvsF[0] = *(const s8v*)&band[W + 1 + lan16][lgrp * 8];
    qvsF[1] = *(const s8v*)&band[W + 1 + lan16][32 + lgrp * 8];
    // loop-top __syncthreads protects these reads before band is overwritten

    f4v accO[4] = {};
    float m_run[4] = {-1e30f, -1e30f, -1e30f, -1e30f};
    float l_run[4] = {0.f, 0.f, 0.f, 0.f};

    auto stage_band = [&](int base) {
        #pragma unroll
        for (int l = 0; l < 4; ++l) {
            int slot = l * 256 + t;
            int row = slot >> 3, col8 = (slot & 7) * 8;
            int trow = base + row;
            us8 o = (us8){0,0,0,0,0,0,0,0};
            if (trow >= 0 && trow < LR)
                o = *(const us8*)(rp + (size_t)trow * DM + col0 + col8);
            *(us8*)&band[row][col8] = o;
        }
    };
    // G = QV @ band^T over the wave's 5-col window; write-once scatter to BD.
    // jl = c*16+lan16 + lgrp*4+rg - 15 (W-independent); band row = (48-W)+c*16+lan16
    auto gpass = [&](const s8v* qf, int mode) {  // mode 0=all, 1=lower(colg<=63), 2=upper(colg>=65)
        const int cbase = 48 - W;
        #pragma unroll
        for (int c = 0; c < 5; ++c) {
            f4v g = {};
            #pragma unroll
            for (int kk = 0; kk < 2; ++kk) {
                s8v bF = *(const s8v*)&band[cbase + c * 16 + lan16][kk * 32 + lgrp * 8];
                g = __builtin_amdgcn_mfma_f32_16x16x32_bf16(qf[kk], bF, g, 0, 0, 0);
            }
            int cl = c * 16 + lan16;
            bool mok = (mode == 0) || (mode == 1 ? (cl <= 15 + W) : (cl >= 17 + W));
            #pragma unroll
            for (int rg = 0; rg < 4; ++rg) {
                int jl = cl + lgrp * 4 + rg - 15;
                if (mok && jl >= 0 && jl < 64)
                    BD[W + lgrp * 4 + rg][jl] = g[rg];
            }
        }
    };

    for (int j0 = 0; j0 < LQ; j0 += 64) {
        const int rel = j0 - i0;
        __syncthreads();
        // stage K (row-major)
        #pragma unroll
        for (int l = 0; l < 2; ++l) {
            int slot = l * 256 + t;
            int row = slot >> 3, col8 = (slot & 7) * 8;
            *(us8*)&Ks[row][col8] = *(const us8*)(kw + (size_t)(j0 + row) * DM + col0 + col8);
        }
        // stage V transposed: lane = d, wave w covers j in [16w,16w+16)
        {
            const int d = t & 63;
            const int jg = w * 16;
            const unsigned short* vp = vw + (size_t)(j0 + jg) * DM + col0 + d;
            us8 v0, v1;
            #pragma unroll
            for (int jj = 0; jj < 8; ++jj) v0[jj] = vp[(size_t)jj * DM];
            #pragma unroll
            for (int jj = 0; jj < 8; ++jj) v1[jj] = vp[(size_t)(jj + 8) * DM];
            *(us8*)&Vt[d][jg] = v0;
            *(us8*)&Vt[d][jg + 8] = v1;
        }
        stage_band(rel <= 0 ? rel + 4031 : rel - 65);
        __syncthreads();

        // AC = QU @ K^T (fragments stay in registers)
        f4v acF[4] = {};
        #pragma unroll
        for (int nf = 0; nf < 4; ++nf)
            #pragma unroll
            for (int kk = 0; kk < 2; ++kk) {
                s8v bF = *(const s8v*)&Ks[nf * 16 + lan16][kk * 32 + lgrp * 8];
                acF[nf] = __builtin_amdgcn_mfma_f32_16x16x32_bf16(quF[kk], bF, acF[nf], 0, 0, 0);
            }
        // BD scatter
        if (rel < 0)      gpass(qvlF, 0);
        else if (rel > 0) gpass(qvsF, 0);
        else {
            gpass(qvlF, 1);
            __syncthreads();
            stage_band(rel - 65);
            __syncthreads();
            gpass(qvsF, 2);
        }
        __builtin_amdgcn_sched_barrier(0);

        // fragment-register online softmax (rows wave-local; no barrier needed)
        const bool isDiag = (rel == 0);
        float fac[4];
        #pragma unroll
        for (int rg = 0; rg < 4; ++rg) {
            const int rr = W + lgrp * 4 + rg;
            float sv[4], rmax = -1e30f;
            #pragma unroll
            for (int nf = 0; nf < 4; ++nf) {
                int jl = nf * 16 + lan16;
                float bd = BD[rr][jl];
                if (isDiag && jl == rr + 1) bd = 0.f;
                sv[nf] = (acF[nf][rg] + bd) * 0.125f;
                rmax = fmaxf(rmax, sv[nf]);
            }
            rmax = fmaxf(rmax, __shfl_xor(rmax, 1, 64));
            rmax = fmaxf(rmax, __shfl_xor(rmax, 2, 64));
            rmax = fmaxf(rmax, __shfl_xor(rmax, 4, 64));
            rmax = fmaxf(rmax, __shfl_xor(rmax, 8, 64));
            float mnew = fmaxf(m_run[rg], rmax);
            fac[rg] = exp2f((m_run[rg] - mnew) * L2E);
            float ps = 0.f;
            #pragma unroll
            for (int nf = 0; nf < 4; ++nf) {
                float p = exp2f((sv[nf] - mnew) * L2E);
                ps += p;
                P[rr][nf * 16 + lan16] = f2bf(p);
            }
            ps += __shfl_xor(ps, 1, 64);
            ps += __shfl_xor(ps, 2, 64);
            ps += __shfl_xor(ps, 4, 64);
            ps += __shfl_xor(ps, 8, 64);
            l_run[rg] = l_run[rg] * fac[rg] + ps;
            m_run[rg] = mnew;
        }
        __builtin_amdgcn_sched_barrier(0);

        // PV (P read is wave-local)
        s8v pF[2];
        pF[0] = *(const s8v*)&P[W + lan16][lgrp * 8];
        pF[1] = *(const s8v*)&P[W + lan16][32 + lgrp * 8];
        #pragma unroll
        for (int nf = 0; nf < 4; ++nf) {
            #pragma unroll
            for (int rg = 0; rg < 4; ++rg) accO[nf][rg] *= fac[rg];
            #pragma unroll
            for (int kk = 0; kk < 2; ++kk) {
                s8v vF = *(const s8v*)&Vt[nf * 16 + lan16][kk * 32 + lgrp * 8];
                accO[nf] = __builtin_amdgcn_mfma_f32_16x16x32_bf16(pF[kk], vF, accO[nf], 0, 0, 0);
            }
        }
    }

    #pragma unroll
    for (int rg = 0; rg < 4; ++rg) {
        float inv = 1.f / l_run[rg];
        const int row = i0 + W + lgrp * 4 + rg;
        #pragma unroll
        for (int nf = 0; nf < 4; ++nf)
            out[(size_t)row * DM + col0 + nf * 16 + lan16] = accO[nf][rg] * inv;
    }
}

// ---------------------------------------------------------------------------
extern "C" void kernel_launch(void* const* d_in, const int* in_sizes, int n_in,
                              void* d_out, int out_size, void* d_ws, size_t ws_size,
                              hipStream_t stream) {
    const float* w  = (const float*)d_in[0];
    const float* Wq = (const float*)d_in[1];
    const float* Wk = (const float*)d_in[2];
    const float* Wv = (const float*)d_in[3];
    const float* Wr = (const float*)d_in[4];
    const float* ub = (const float*)d_in[5];
    const float* vb = (const float*)d_in[6];
    float* out = (float*)d_out;

    unsigned short* wbf = (unsigned short*)d_ws;              // 2M
    unsigned short* Wqb = wbf + 2097152;                      // 1M each
    unsigned short* Wkb = Wqb + 1048576;
    unsigned short* Wvb = Wkb + 1048576;
    unsigned short* Wrb = Wvb + 1048576;
    unsigned short* q   = Wrb + 1048576;                      // 2M
    unsigned short* kk  = q  + 2097152;
    unsigned short* vv  = kk + 2097152;
    unsigned short* rp  = vv + 2097152;                       // LR*DM
    unsigned short* r   = rp + (size_t)LR * DM;               // LR*DM

    dim3 blk(256);
    hipLaunchKernelGGL(cast_all, dim3(3072), blk, 0, stream, w, Wq, Wk, Wv, Wr, wbf);
    hipLaunchKernelGGL(r_kernel, dim3(8190), blk, 0, stream, r);
    hipLaunchKernelGGL(proj_gemm, dim3(16, 24), blk, 0, stream,
                       wbf, Wqb, Wkb, Wvb, q, kk, vv, LQ);
    hipLaunchKernelGGL(proj_gemm, dim3(32, 8), blk, 0, stream,
                       r, Wrb, Wrb, Wrb, rp, rp, rp, LR);
    hipLaunchKernelGGL(attn_mfma, dim3(32, 16), blk, 0, stream,
                       q, kk, vv, rp, ub, vb, out);
}

// Round 4
// 170.229 us; speedup vs baseline: 72.0524x; 1.3111x over previous
//
#include <hip/hip_runtime.h>
#include <math.h>

#define LQ 2048
#define DM 1024
#define NH 16
#define DH 64
#define LR 4095  // 2*LQ-1

typedef __attribute__((ext_vector_type(4))) float f4v;
typedef __attribute__((ext_vector_type(8))) short s8v;
typedef __attribute__((ext_vector_type(2))) unsigned short us2;
typedef __attribute__((ext_vector_type(4))) unsigned short us4;
typedef __attribute__((ext_vector_type(8))) unsigned short us8;

__device__ __forceinline__ unsigned short f2bf(float x) {
    unsigned int u = __float_as_uint(x);
    return (unsigned short)((u + 0x7FFFu + ((u >> 16) & 1u)) >> 16);
}
__device__ __forceinline__ float bf2f(unsigned short s) {
    return __uint_as_float(((unsigned int)s) << 16);
}

// DPP rotate within 16-lane row (VALU pipe, replaces ds_swizzle shuffles)
template<int CTRL>
__device__ __forceinline__ float rot16(float x) {
    return __uint_as_float((unsigned)__builtin_amdgcn_update_dpp(
        0, (int)__float_as_uint(x), CTRL, 0xF, 0xF, false));
}

#define GLOAD16(g, l) __builtin_amdgcn_global_load_lds((g), (l), 16, 0, 0)

// ---------------------------------------------------------------------------
// cast f32 inputs -> one contiguous bf16 region: [w(2M) | Wq | Wk | Wv | Wr]
// ---------------------------------------------------------------------------
__global__ __launch_bounds__(256)
void cast_all(const float* __restrict__ w, const float* __restrict__ Wq,
              const float* __restrict__ Wk, const float* __restrict__ Wv,
              const float* __restrict__ Wr, unsigned short* __restrict__ dst) {
    size_t e0 = ((size_t)blockIdx.x * 256 + threadIdx.x) * 8;
    const float* src;
    if (e0 < (size_t)LQ * DM) src = w + e0;
    else {
        size_t ro = e0 - (size_t)LQ * DM;
        int wi = (int)(ro >> 20);
        size_t off = ro & 1048575;
        src = (wi == 0 ? Wq : wi == 1 ? Wk : wi == 2 ? Wv : Wr) + off;
    }
    f4v a = *(const f4v*)src;
    f4v b = *(const f4v*)(src + 4);
    us8 o;
    o[0]=f2bf(a[0]); o[1]=f2bf(a[1]); o[2]=f2bf(a[2]); o[3]=f2bf(a[3]);
    o[4]=f2bf(b[0]); o[5]=f2bf(b[1]); o[6]=f2bf(b[2]); o[7]=f2bf(b[3]);
    *(us8*)(dst + e0) = o;
}

// ---------------------------------------------------------------------------
// sinusoidal r [LR x DM] bf16; one thread per (pos, freq) pair
// ---------------------------------------------------------------------------
__global__ __launch_bounds__(256)
void r_kernel(unsigned short* __restrict__ r) {
    int tg = blockIdx.x * 256 + threadIdx.x;   // 4095*512 threads exactly
    int gm = tg >> 9, c2 = tg & 511;
    float invf = expf(-(float)c2 * (9.210340371976184f / 512.0f));
    float ang = (float)(gm - (LQ - 1)) * invf;
    us2 o; o[0] = f2bf(sinf(ang)); o[1] = f2bf(cosf(ang));
    *(us2*)&r[(size_t)gm * DM + c2 * 2] = o;
}

// ---------------------------------------------------------------------------
// C[M,N]=A@B^T bf16, m97 structure: 128x128 tile, BK=64, global_load_lds(16),
// linear LDS, 4 waves each owning a 64x64 quadrant (4x4 16x16x32 frags).
// ---------------------------------------------------------------------------
__global__ __launch_bounds__(256)
void proj_gemm(const unsigned short* __restrict__ A,
               const unsigned short* __restrict__ b0, const unsigned short* __restrict__ b1,
               const unsigned short* __restrict__ b2,
               unsigned short* __restrict__ c0, unsigned short* __restrict__ c1,
               unsigned short* __restrict__ c2_, int M) {
    __shared__ unsigned short As[128 * 64];
    __shared__ unsigned short Bs[128 * 64];
    const int mat = blockIdx.y >> 3;
    const int m0 = blockIdx.x * 128, n0 = (blockIdx.y & 7) * 128;
    const unsigned short* B = mat == 0 ? b0 : mat == 1 ? b1 : b2;
    unsigned short* C = mat == 0 ? c0 : mat == 1 ? c1 : c2_;
    const int t = threadIdx.x;
    const int w = t >> 6, lan16 = t & 15, lgrp = (t & 63) >> 4;
    const int wm = (w >> 1) * 64, wn = (w & 1) * 64;
    f4v acc[4][4] = {};

    for (int k0 = 0; k0 < DM; k0 += 64) {
        #pragma unroll
        for (int it = 0; it < 4; ++it) {
            int e = it * 256 + t;            // lane l of wave w -> e = it*256+w*64+l
            int row = e >> 3, c8 = (e & 7) * 8;
            int gm = m0 + row; if (gm > M - 1) gm = M - 1;
            GLOAD16(A + (size_t)gm * DM + k0 + c8,
                    (char*)As + (size_t)(it * 256 + w * 64) * 16);
            GLOAD16(B + (size_t)(n0 + row) * DM + k0 + c8,
                    (char*)Bs + (size_t)(it * 256 + w * 64) * 16);
        }
        __syncthreads();
        #pragma unroll
        for (int kk = 0; kk < 2; ++kk) {
            s8v aF[4], bF[4];
            #pragma unroll
            for (int i = 0; i < 4; ++i) {
                aF[i] = *(const s8v*)&As[(wm + i * 16 + lan16) * 64 + kk * 32 + lgrp * 8];
                bF[i] = *(const s8v*)&Bs[(wn + i * 16 + lan16) * 64 + kk * 32 + lgrp * 8];
            }
            #pragma unroll
            for (int i = 0; i < 4; ++i)
                #pragma unroll
                for (int j = 0; j < 4; ++j)
                    acc[i][j] = __builtin_amdgcn_mfma_f32_16x16x32_bf16(aF[i], bF[j], acc[i][j], 0, 0, 0);
        }
        __syncthreads();
    }
    #pragma unroll
    for (int i = 0; i < 4; ++i)
        #pragma unroll
        for (int j = 0; j < 4; ++j)
            #pragma unroll
            for (int rg = 0; rg < 4; ++rg) {
                int row = m0 + wm + i * 16 + lgrp * 4 + rg;
                if (row < M)
                    C[(size_t)row * DM + n0 + wn + j * 16 + lan16] = f2bf(acc[i][j][rg]);
            }
}

// ---------------------------------------------------------------------------
// Fused rel-attention. Block = (head, 64 q rows), j-tiles of 64.
// Fixed-max softmax (logits bounded; p = exp(s*0.125 - 4)), masks via band
// OOB zero-fill, BD sheared into wave-private Gtw (b64 stores), all
// post-MFMA communication intra-wave.
// ---------------------------------------------------------------------------
__global__ __launch_bounds__(256, 3)
void attn_mfma(const unsigned short* __restrict__ q, const unsigned short* __restrict__ kw,
               const unsigned short* __restrict__ vw, const unsigned short* __restrict__ rp,
               const float* __restrict__ ub, const float* __restrict__ vb,
               float* __restrict__ out) {
    __shared__ unsigned short Ks[64][72];
    __shared__ unsigned short Vt[64][72];
    __shared__ unsigned short band[128][72];
    __shared__ unsigned short Gtw[4 * 80 * 20];   // wave-private sheared G/P

    // XCD-aware swizzle: 512 blocks = 8 XCDs x 64, head-major chunks
    const int dd = blockIdx.x;
    const int f = (dd & 7) * 64 + (dd >> 3);
    const int h = f >> 5;
    const int i0 = (f & 31) * 64;
    const int col0 = h * DH;
    const int t = threadIdx.x;
    const int w = t >> 6, lan16 = t & 15, lgrp = (t & 63) >> 4;
    const int W = w * 16;
    const float C1 = 0.125f * 1.4426950408889634f;   // scale * log2(e)
    const float C0 = -4.0f * 1.4426950408889634f;    // fixed-max shift

    unsigned short* gw = &Gtw[w * 1600];

    s8v quF[2], qvlF[2], qvsF[2];
    // stage QU = q + ub into band rows 0..63, preload frags
    #pragma unroll
    for (int l = 0; l < 2; ++l) {
        int slot = l * 256 + t;
        int row = slot >> 3, col8 = (slot & 7) * 8;
        us8 qv = *(const us8*)(q + (size_t)(i0 + row) * DM + col0 + col8);
        us8 o;
        #pragma unroll
        for (int i = 0; i < 8; ++i) o[i] = f2bf(bf2f(qv[i]) + ub[col0 + col8 + i]);
        *(us8*)&band[row][col8] = o;
    }
    __syncthreads();
    quF[0] = *(const s8v*)&band[W + lan16][lgrp * 8];
    quF[1] = *(const s8v*)&band[W + lan16][32 + lgrp * 8];
    __syncthreads();
    // stage QV rows 0..64 (row 64 = next tile's first row; zero past end)
    #pragma unroll
    for (int l = 0; l < 3; ++l) {
        int slot = l * 256 + t;
        if (slot < 65 * 8) {
            int row = slot >> 3, col8 = (slot & 7) * 8;
            int gi = i0 + row;
            us8 o = (us8){0,0,0,0,0,0,0,0};
            if (gi < LQ) {
                us8 qv = *(const us8*)(q + (size_t)gi * DM + col0 + col8);
                #pragma unroll
                for (int i = 0; i < 8; ++i) o[i] = f2bf(bf2f(qv[i]) + vb[col0 + col8 + i]);
            }
            *(us8*)&band[row][col8] = o;
        }
    }
    __syncthreads();
    qvlF[0] = *(const s8v*)&band[W + lan16][lgrp * 8];
    qvlF[1] = *(const s8v*)&band[W + lan16][32 + lgrp * 8];
    qvsF[0] = *(const s8v*)&band[W + 1 + lan16][lgrp * 8];
    qvsF[1] = *(const s8v*)&band[W + 1 + lan16][32 + lgrp * 8];

    f4v accO[4] = {};
    float lsum[4] = {0.f, 0.f, 0.f, 0.f};

    auto stage_band = [&](int base) {
        #pragma unroll
        for (int l = 0; l < 4; ++l) {
            int slot = l * 256 + t;
            int row = slot >> 3, col8 = (slot & 7) * 8;
            int trow = base + row;
            us8 o = (us8){0,0,0,0,0,0,0,0};
            if (trow >= 0 && trow < LR)
                o = *(const us8*)(rp + (size_t)trow * DM + col0 + col8);
            *(us8*)&band[row][col8] = o;
        }
    };

    const int cbase = 48 - W;

    for (int j0 = 0; j0 < LQ; j0 += 64) {
        const int rel = j0 - i0;
        __syncthreads();    // B1: prior tile's frag reads done
        // stage K (row-major)
        #pragma unroll
        for (int l = 0; l < 2; ++l) {
            int slot = l * 256 + t;
            int row = slot >> 3, col8 = (slot & 7) * 8;
            *(us8*)&Ks[row][col8] = *(const us8*)(kw + (size_t)(j0 + row) * DM + col0 + col8);
        }
        // stage V transposed: lane = d, wave w covers j in [16w,16w+16)
        {
            const int d = t & 63;
            const int jg = w * 16;
            const unsigned short* vp = vw + (size_t)(j0 + jg) * DM + col0 + d;
            us8 v0, v1;
            #pragma unroll
            for (int jj = 0; jj < 8; ++jj) v0[jj] = vp[(size_t)jj * DM];
            #pragma unroll
            for (int jj = 0; jj < 8; ++jj) v1[jj] = vp[(size_t)(jj + 8) * DM];
            *(us8*)&Vt[d][jg] = v0;
            *(us8*)&Vt[d][jg + 8] = v1;
        }
        // band OOB zero-fill == exact lower/upper region masks
        stage_band(rel <= 0 ? rel + 4031 : rel - 65);
        __syncthreads();    // B2

        // AC = QU @ K^T (fragments stay in registers)
        f4v acF[4] = {};
        #pragma unroll
        for (int nf = 0; nf < 4; ++nf)
            #pragma unroll
            for (int kk = 0; kk < 2; ++kk) {
                s8v bF = *(const s8v*)&Ks[nf * 16 + lan16][kk * 32 + lgrp * 8];
                acF[nf] = __builtin_amdgcn_mfma_f32_16x16x32_bf16(quF[kk], bF, acF[nf], 0, 0, 0);
            }
        // BD: G = QV @ band^T over the wave's 5-frag window
        f4v g[5] = {};
        auto gmm = [&](const s8v* qf) {
            #pragma unroll
            for (int c = 0; c < 5; ++c)
                #pragma unroll
                for (int kk = 0; kk < 2; ++kk) {
                    s8v bF = *(const s8v*)&band[cbase + c * 16 + lan16][kk * 32 + lgrp * 8];
                    g[c] = __builtin_amdgcn_mfma_f32_16x16x32_bf16(qf[kk], bF, g[c], 0, 0, 0);
                }
        };
        if (rel <= 0) gmm(qvlF);
        else          gmm(qvsF);
        if (rel == 0) {   // diag tile: second band, accumulate (regions disjoint)
            __syncthreads();
            stage_band(-65);
            __syncthreads();
            gmm(qvsF);
        }
        // sheared store: slot [B'=cl][rhat], b64-packed along rows
        #pragma unroll
        for (int c = 0; c < 5; ++c) {
            us4 o;
            #pragma unroll
            for (int rg = 0; rg < 4; ++rg) o[rg] = f2bf(g[c][rg]);
            *(us4*)&gw[(c * 16 + lan16) * 20 + lgrp * 4] = o;
        }
        asm volatile("s_waitcnt lgkmcnt(0)" ::: "memory");
        __builtin_amdgcn_sched_barrier(0);

        // fixed-max softmax, P written back into the same Gtw slots
        #pragma unroll
        for (int rg = 0; rg < 4; ++rg) {
            const int rhat = lgrp * 4 + rg;
            #pragma unroll
            for (int nf = 0; nf < 4; ++nf) {
                int jl = nf * 16 + lan16;
                int ad = (jl - rhat + 15) * 20 + rhat;
                float bd = bf2f(gw[ad]);
                float p = exp2f((acF[nf][rg] + bd) * C1 + C0);
                lsum[rg] += p;
                gw[ad] = f2bf(p);
            }
        }
        asm volatile("s_waitcnt lgkmcnt(0)" ::: "memory");
        __builtin_amdgcn_sched_barrier(0);

        // PV: gather A-frags from sheared P, MFMA with Vt
        s8v pF[2];
        #pragma unroll
        for (int kk = 0; kk < 2; ++kk) {
            us8 tmp;
            #pragma unroll
            for (int e = 0; e < 8; ++e) {
                int jl = kk * 32 + lgrp * 8 + e;
                tmp[e] = gw[(jl - lan16 + 15) * 20 + lan16];
            }
            pF[kk] = (s8v)tmp;
        }
        #pragma unroll
        for (int nf = 0; nf < 4; ++nf)
            #pragma unroll
            for (int kk = 0; kk < 2; ++kk) {
                s8v vF = *(const s8v*)&Vt[nf * 16 + lan16][kk * 32 + lgrp * 8];
                accO[nf] = __builtin_amdgcn_mfma_f32_16x16x32_bf16(pF[kk], vF, accO[nf], 0, 0, 0);
            }
    }

    // epilogue: row-sum via DPP ror over the 16-lane row, normalize, store
    #pragma unroll
    for (int rg = 0; rg < 4; ++rg) {
        float s = lsum[rg];
        s += rot16<0x121>(s);   // ror:1
        s += rot16<0x122>(s);   // ror:2
        s += rot16<0x124>(s);   // ror:4
        s += rot16<0x128>(s);   // ror:8
        float inv = 1.f / s;
        const int row = i0 + W + lgrp * 4 + rg;
        #pragma unroll
        for (int nf = 0; nf < 4; ++nf)
            out[(size_t)row * DM + col0 + nf * 16 + lan16] = accO[nf][rg] * inv;
    }
}

// ---------------------------------------------------------------------------
extern "C" void kernel_launch(void* const* d_in, const int* in_sizes, int n_in,
                              void* d_out, int out_size, void* d_ws, size_t ws_size,
                              hipStream_t stream) {
    const float* w  = (const float*)d_in[0];
    const float* Wq = (const float*)d_in[1];
    const float* Wk = (const float*)d_in[2];
    const float* Wv = (const float*)d_in[3];
    const float* Wr = (const float*)d_in[4];
    const float* ub = (const float*)d_in[5];
    const float* vb = (const float*)d_in[6];
    float* out = (float*)d_out;

    unsigned short* wbf = (unsigned short*)d_ws;              // 2M
    unsigned short* Wqb = wbf + 2097152;                      // 1M each
    unsigned short* Wkb = Wqb + 1048576;
    unsigned short* Wvb = Wkb + 1048576;
    unsigned short* Wrb = Wvb + 1048576;
    unsigned short* q   = Wrb + 1048576;                      // 2M
    unsigned short* kk  = q  + 2097152;
    unsigned short* vv  = kk + 2097152;
    unsigned short* rp  = vv + 2097152;                       // LR*DM
    unsigned short* r   = rp + (size_t)LR * DM;               // LR*DM

    dim3 blk(256);
    hipLaunchKernelGGL(cast_all, dim3(3072), blk, 0, stream, w, Wq, Wk, Wv, Wr, wbf);
    hipLaunchKernelGGL(r_kernel, dim3(8190), blk, 0, stream, r);
    hipLaunchKernelGGL(proj_gemm, dim3(16, 24), blk, 0, stream,
                       wbf, Wqb, Wkb, Wvb, q, kk, vv, LQ);
    hipLaunchKernelGGL(proj_gemm, dim3(32, 8), blk, 0, stream,
                       r, Wrb, Wrb, Wrb, rp, rp, rp, LR);
    hipLaunchKernelGGL(attn_mfma, dim3(512), blk, 0, stream,
                       q, kk, vv, rp, ub, vb, out);
}

// Round 6
// 146.839 us; speedup vs baseline: 83.5296x; 1.1593x over previous
//
#include <hip/hip_runtime.h>
#include <math.h>

#define LQ 2048
#define DM 1024
#define NH 16
#define DH 64
#define LR 4095  // 2*LQ-1

typedef __attribute__((ext_vector_type(4))) float f4v;
typedef __attribute__((ext_vector_type(8))) short s8v;
typedef __attribute__((ext_vector_type(2))) unsigned short us2;
typedef __attribute__((ext_vector_type(8))) unsigned short us8;
typedef __attribute__((ext_vector_type(2))) unsigned int u32x2;

__device__ __forceinline__ unsigned short f2bf(float x) {
    unsigned int u = __float_as_uint(x);
    return (unsigned short)((u + 0x7FFFu + ((u >> 16) & 1u)) >> 16);
}
__device__ __forceinline__ float bf2f(unsigned short s) {
    return __uint_as_float(((unsigned int)s) << 16);
}
__device__ __forceinline__ unsigned cvtpk(float lo, float hi) {
    unsigned r;
    asm("v_cvt_pk_bf16_f32 %0, %1, %2" : "=v"(r) : "v"(lo), "v"(hi));
    return r;
}
// DPP rotate within 16-lane row (VALU pipe)
template<int CTRL>
__device__ __forceinline__ float rot16(float x) {
    return __uint_as_float((unsigned)__builtin_amdgcn_update_dpp(
        0, (int)__float_as_uint(x), CTRL, 0xF, 0xF, false));
}
#define GLOAD16(g, l) __builtin_amdgcn_global_load_lds((g), (l), 16, 0, 0)
// fence for cross-lane LDS handoff within a wave (load-bearing! see r5 NaN)
#define WAVE_LDS_FENCE() do { \
    asm volatile("s_waitcnt lgkmcnt(0)" ::: "memory"); \
    __builtin_amdgcn_sched_barrier(0); } while (0)

// swizzled LDS helpers: tiles are [rows][64] bf16, byte ^= (row&7)<<4
__device__ __forceinline__ void sw_store8(unsigned short* base, int row, int c8, us8 v) {
    int byte = (row * 128 + c8 * 16) ^ ((row & 7) << 4);
    *(us8*)((char*)base + byte) = v;
}
__device__ __forceinline__ s8v sw_read8(const unsigned short* base, int row, int colshort) {
    int byte = (row * 128 + colshort * 2) ^ ((row & 7) << 4);
    return *(const s8v*)((const char*)base + byte);
}

// ---------------------------------------------------------------------------
// cast f32 inputs -> contiguous bf16: [w(2M) | Wq | Wk | Wv | Wr]
// ---------------------------------------------------------------------------
__global__ __launch_bounds__(256)
void cast_all(const float* __restrict__ w, const float* __restrict__ Wq,
              const float* __restrict__ Wk, const float* __restrict__ Wv,
              const float* __restrict__ Wr, unsigned short* __restrict__ dst) {
    size_t e0 = ((size_t)blockIdx.x * 256 + threadIdx.x) * 8;
    const float* src;
    if (e0 < (size_t)LQ * DM) src = w + e0;
    else {
        size_t ro = e0 - (size_t)LQ * DM;
        int wi = (int)(ro >> 20);
        size_t off = ro & 1048575;
        src = (wi == 0 ? Wq : wi == 1 ? Wk : wi == 2 ? Wv : Wr) + off;
    }
    f4v a = *(const f4v*)src;
    f4v b = *(const f4v*)(src + 4);
    us8 o;
    o[0]=f2bf(a[0]); o[1]=f2bf(a[1]); o[2]=f2bf(a[2]); o[3]=f2bf(a[3]);
    o[4]=f2bf(b[0]); o[5]=f2bf(b[1]); o[6]=f2bf(b[2]); o[7]=f2bf(b[3]);
    *(us8*)(dst + e0) = o;
}

// ---------------------------------------------------------------------------
// sinusoidal r [LR x DM] bf16
// ---------------------------------------------------------------------------
__global__ __launch_bounds__(256)
void r_kernel(unsigned short* __restrict__ r) {
    int tg = blockIdx.x * 256 + threadIdx.x;   // LR*512 threads exactly
    int gm = tg >> 9, c2 = tg & 511;
    float invf = expf(-(float)c2 * (9.210340371976184f / 512.0f));
    float ang = (float)(gm - (LQ - 1)) * invf;
    us2 o; o[0] = f2bf(sinf(ang)); o[1] = f2bf(cosf(ang));
    *(us2*)&r[(size_t)gm * DM + c2 * 2] = o;
}

// ---------------------------------------------------------------------------
// C[M,N]=A@B^T bf16, 64x128 tile, BK=64, global_load_lds(16), linear LDS.
// 4 waves: quadrant wm=(w>>1)*32, wn=(w&1)*64, acc 2x4 frags.
// mat==2 writes C transposed (vt[n][m]) for the attention V path.
// ---------------------------------------------------------------------------
__global__ __launch_bounds__(256)
void proj_gemm(const unsigned short* __restrict__ A,
               const unsigned short* __restrict__ b0, const unsigned short* __restrict__ b1,
               const unsigned short* __restrict__ b2,
               unsigned short* __restrict__ c0, unsigned short* __restrict__ c1,
               unsigned short* __restrict__ c2_, int M) {
    __shared__ unsigned short As[64 * 64];
    __shared__ unsigned short Bs[128 * 64];
    const int mat = blockIdx.y >> 3;
    const int m0 = blockIdx.x * 64, n0 = (blockIdx.y & 7) * 128;
    const unsigned short* B = mat == 0 ? b0 : mat == 1 ? b1 : b2;
    unsigned short* C = mat == 0 ? c0 : mat == 1 ? c1 : c2_;
    const int t = threadIdx.x;
    const int w = t >> 6, lan16 = t & 15, lgrp = (t & 63) >> 4;
    const int wm = (w >> 1) * 32, wn = (w & 1) * 64;
    f4v acc[2][4] = {};

    for (int k0 = 0; k0 < DM; k0 += 64) {
        #pragma unroll
        for (int it = 0; it < 2; ++it) {
            int slot = it * 256 + t;
            int row = slot >> 3, c8 = slot & 7;
            int gm = m0 + row; if (gm > M - 1) gm = M - 1;
            GLOAD16(A + (size_t)gm * DM + k0 + c8 * 8,
                    (char*)As + (size_t)(it * 256 + w * 64) * 16);
        }
        #pragma unroll
        for (int it = 0; it < 4; ++it) {
            int slot = it * 256 + t;
            int row = slot >> 3, c8 = slot & 7;
            GLOAD16(B + (size_t)(n0 + row) * DM + k0 + c8 * 8,
                    (char*)Bs + (size_t)(it * 256 + w * 64) * 16);
        }
        __syncthreads();
        #pragma unroll
        for (int kk = 0; kk < 2; ++kk) {
            s8v aF[2], bF[4];
            #pragma unroll
            for (int i = 0; i < 2; ++i)
                aF[i] = *(const s8v*)&As[(wm + i * 16 + lan16) * 64 + kk * 32 + lgrp * 8];
            #pragma unroll
            for (int j = 0; j < 4; ++j)
                bF[j] = *(const s8v*)&Bs[(wn + j * 16 + lan16) * 64 + kk * 32 + lgrp * 8];
            #pragma unroll
            for (int i = 0; i < 2; ++i)
                #pragma unroll
                for (int j = 0; j < 4; ++j)
                    acc[i][j] = __builtin_amdgcn_mfma_f32_16x16x32_bf16(aF[i], bF[j], acc[i][j], 0, 0, 0);
        }
        __syncthreads();
    }
    if (mat != 2) {
        #pragma unroll
        for (int i = 0; i < 2; ++i)
            #pragma unroll
            for (int j = 0; j < 4; ++j)
                #pragma unroll
                for (int rg = 0; rg < 4; ++rg) {
                    int row = m0 + wm + i * 16 + lgrp * 4 + rg;
                    if (row < M)
                        C[(size_t)row * DM + n0 + wn + j * 16 + lan16] = f2bf(acc[i][j][rg]);
                }
    } else {
        // transposed store: vt[n][m], b64-packed along m
        #pragma unroll
        for (int i = 0; i < 2; ++i)
            #pragma unroll
            for (int j = 0; j < 4; ++j) {
                int n = n0 + wn + j * 16 + lan16;
                int m = m0 + wm + i * 16 + lgrp * 4;
                u32x2 pp;
                pp[0] = cvtpk(acc[i][j][0], acc[i][j][1]);
                pp[1] = cvtpk(acc[i][j][2], acc[i][j][3]);
                *(u32x2*)&C[(size_t)n * LQ + m] = pp;
            }
    }
}

// ---------------------------------------------------------------------------
// Fused rel-attention, split-j. Block = (head, 64 q rows, j-half).
// Fixed-max softmax; band OOB zero == exact region masks; G sheared into
// wave-private Gtw; P stored once as P^T; swizzled K/V/band LDS.
// ---------------------------------------------------------------------------
__global__ __launch_bounds__(256, 3)
void attn_mfma(const unsigned short* __restrict__ q, const unsigned short* __restrict__ kkg,
               const unsigned short* __restrict__ vtg, const unsigned short* __restrict__ rp,
               const float* __restrict__ ub, const float* __restrict__ vb,
               float* __restrict__ Oa, float* __restrict__ Ob,
               float* __restrict__ la, float* __restrict__ lb) {
    __shared__ unsigned short Ks[64 * 64];
    __shared__ unsigned short Vt[64 * 64];
    __shared__ unsigned short band[128 * 64];
    __shared__ unsigned short Gtw[4][80 * 18];
    __shared__ unsigned short Pt[4][64 * 18];

    // XCD swizzle: 1024 = 8 x 128 (2 heads per XCD chunk)
    const int dd = blockIdx.x;
    const int f = (dd & 7) * 128 + (dd >> 3);
    const int h = f >> 6;
    const int sp = (f >> 5) & 1;
    const int i0 = (f & 31) * 64;
    const int col0 = h * DH;
    float* Op = sp ? Ob : Oa;
    float* lp = sp ? lb : la;
    const int jbeg = sp * 1024;

    const int t = threadIdx.x;
    const int w = t >> 6, lan16 = t & 15, lgrp = (t & 63) >> 4;
    const int W = w * 16;
    const float C1 = 0.125f * 1.4426950408889634f;
    const float C0 = -4.0f * 1.4426950408889634f;

    unsigned short* gw = Gtw[w];
    unsigned short* pw = Pt[w];

    s8v quF[2], qvlF[2], qvsF[2];
    // stage QU = q + ub into Ks (linear), preload frags
    #pragma unroll
    for (int l = 0; l < 2; ++l) {
        int slot = l * 256 + t;
        int row = slot >> 3, c8 = slot & 7;
        us8 qv = *(const us8*)(q + (size_t)(i0 + row) * DM + col0 + c8 * 8);
        us8 o;
        #pragma unroll
        for (int i = 0; i < 8; ++i) o[i] = f2bf(bf2f(qv[i]) + ub[col0 + c8 * 8 + i]);
        *(us8*)&Ks[row * 64 + c8 * 8] = o;
    }
    __syncthreads();
    quF[0] = *(const s8v*)&Ks[(W + lan16) * 64 + lgrp * 8];
    quF[1] = *(const s8v*)&Ks[(W + lan16) * 64 + 32 + lgrp * 8];
    __syncthreads();
    // stage QV rows 0..64 into band (linear)
    #pragma unroll
    for (int l = 0; l < 3; ++l) {
        int slot = l * 256 + t;
        if (slot < 65 * 8) {
            int row = slot >> 3, c8 = slot & 7;
            int gi = i0 + row;
            us8 o = (us8){0,0,0,0,0,0,0,0};
            if (gi < LQ) {
                us8 qv = *(const us8*)(q + (size_t)gi * DM + col0 + c8 * 8);
                #pragma unroll
                for (int i = 0; i < 8; ++i) o[i] = f2bf(bf2f(qv[i]) + vb[col0 + c8 * 8 + i]);
            }
            *(us8*)&band[row * 64 + c8 * 8] = o;
        }
    }
    __syncthreads();
    qvlF[0] = *(const s8v*)&band[(W + lan16) * 64 + lgrp * 8];
    qvlF[1] = *(const s8v*)&band[(W + lan16) * 64 + 32 + lgrp * 8];
    qvsF[0] = *(const s8v*)&band[(W + 1 + lan16) * 64 + lgrp * 8];
    qvsF[1] = *(const s8v*)&band[(W + 1 + lan16) * 64 + 32 + lgrp * 8];

    f4v accO[4] = {};
    float lsum[4] = {0.f, 0.f, 0.f, 0.f};
    const int cbase = 48 - W;

    auto stage_band = [&](int base) {
        #pragma unroll
        for (int l = 0; l < 4; ++l) {
            int slot = l * 256 + t;
            int row = slot >> 3, c8 = slot & 7;
            int trow = base + row;
            us8 v = (us8){0,0,0,0,0,0,0,0};
            if (trow >= 0 && trow < LR)
                v = *(const us8*)(rp + (size_t)trow * DM + col0 + c8 * 8);
            sw_store8(band, row, c8, v);
        }
    };

    for (int tt = 0; tt < 16; ++tt) {
        const int j0 = jbeg + tt * 64;
        const int rel = j0 - i0;
        __syncthreads();   // B1: prior tile reads done
        // stage K (swizzled)
        #pragma unroll
        for (int l = 0; l < 2; ++l) {
            int slot = l * 256 + t;
            int row = slot >> 3, c8 = slot & 7;
            us8 v = *(const us8*)(kkg + (size_t)(j0 + row) * DM + col0 + c8 * 8);
            sw_store8(Ks, row, c8, v);
        }
        // stage V^T from pre-transposed global vt (swizzled)
        #pragma unroll
        for (int l = 0; l < 2; ++l) {
            int slot = l * 256 + t;
            int row = slot >> 3, c8 = slot & 7;
            us8 v = *(const us8*)(vtg + (size_t)(col0 + row) * LQ + j0 + c8 * 8);
            sw_store8(Vt, row, c8, v);
        }
        stage_band(rel <= 0 ? rel + 4031 : rel - 65);
        __syncthreads();   // B2

        // AC = QU @ K^T
        f4v acF[4] = {};
        #pragma unroll
        for (int nf = 0; nf < 4; ++nf)
            #pragma unroll
            for (int kk = 0; kk < 2; ++kk) {
                s8v bF = sw_read8(Ks, nf * 16 + lan16, kk * 32 + lgrp * 8);
                acF[nf] = __builtin_amdgcn_mfma_f32_16x16x32_bf16(quF[kk], bF, acF[nf], 0, 0, 0);
            }
        // BD: G = QV @ band^T over wave's 5-frag window
        f4v g[5] = {};
        auto gmm = [&](const s8v* qf) {
            #pragma unroll
            for (int c = 0; c < 5; ++c)
                #pragma unroll
                for (int kk = 0; kk < 2; ++kk) {
                    s8v bF = sw_read8(band, cbase + c * 16 + lan16, kk * 32 + lgrp * 8);
                    g[c] = __builtin_amdgcn_mfma_f32_16x16x32_bf16(qf[kk], bF, g[c], 0, 0, 0);
                }
        };
        if (rel <= 0) gmm(qvlF);
        else          gmm(qvsF);
        if (rel == 0) {     // diagonal: second band, disjoint regions accumulate
            __syncthreads();
            stage_band(-65);
            __syncthreads();
            gmm(qvsF);
        }
        // sheared G store (b32 cvt_pk pairs), pitch 18
        #pragma unroll
        for (int c = 0; c < 5; ++c) {
            int cl = c * 16 + lan16;
            *(unsigned*)&gw[cl * 18 + lgrp * 4]     = cvtpk(g[c][0], g[c][1]);
            *(unsigned*)&gw[cl * 18 + lgrp * 4 + 2] = cvtpk(g[c][2], g[c][3]);
        }
        WAVE_LDS_FENCE();   // cross-lane handoff: G stores -> softmax reads

        // fixed-max softmax; P -> P^T[jl][rhat] (pitch 18)
        float p[4][4];
        #pragma unroll
        for (int rg = 0; rg < 4; ++rg) {
            const int rhat = lgrp * 4 + rg;
            #pragma unroll
            for (int nf = 0; nf < 4; ++nf) {
                int jl = nf * 16 + lan16;
                float bd = bf2f(gw[(jl - rhat + 15) * 18 + rhat]);
                float pp = exp2f(fmaf(acF[nf][rg] + bd, C1, C0));
                p[nf][rg] = pp;
                lsum[rg] += pp;
            }
        }
        #pragma unroll
        for (int nf = 0; nf < 4; ++nf) {
            int jl = nf * 16 + lan16;
            *(unsigned*)&pw[jl * 18 + lgrp * 4]     = cvtpk(p[nf][0], p[nf][1]);
            *(unsigned*)&pw[jl * 18 + lgrp * 4 + 2] = cvtpk(p[nf][2], p[nf][3]);
        }
        WAVE_LDS_FENCE();   // cross-lane handoff: P stores -> pF gather

        // pF gather from P^T (conflict-free pitch-18 pattern)
        s8v pF[2];
        #pragma unroll
        for (int kk = 0; kk < 2; ++kk) {
            us8 tmp;
            #pragma unroll
            for (int e = 0; e < 8; ++e)
                tmp[e] = pw[(kk * 32 + lgrp * 8 + e) * 18 + lan16];
            pF[kk] = (s8v)tmp;
        }
        // PV
        #pragma unroll
        for (int nf = 0; nf < 4; ++nf)
            #pragma unroll
            for (int kk = 0; kk < 2; ++kk) {
                s8v vF = sw_read8(Vt, nf * 16 + lan16, kk * 32 + lgrp * 8);
                accO[nf] = __builtin_amdgcn_mfma_f32_16x16x32_bf16(pF[kk], vF, accO[nf], 0, 0, 0);
            }
    }

    // epilogue: partial row-sums (DPP) + unnormalized O partial
    #pragma unroll
    for (int rg = 0; rg < 4; ++rg) {
        float s = lsum[rg];
        s += rot16<0x121>(s);
        s += rot16<0x122>(s);
        s += rot16<0x124>(s);
        s += rot16<0x128>(s);
        const int row = i0 + W + lgrp * 4 + rg;
        if (lan16 == 0) lp[h * LQ + row] = s;
        #pragma unroll
        for (int nf = 0; nf < 4; ++nf)
            Op[(size_t)row * DM + col0 + nf * 16 + lan16] = accO[nf][rg];
    }
}

// ---------------------------------------------------------------------------
// combine: out = (Oa + Ob) / (la + lb)
// ---------------------------------------------------------------------------
__global__ __launch_bounds__(256)
void combine(const float* __restrict__ Oa, const float* __restrict__ Ob,
             const float* __restrict__ la, const float* __restrict__ lb,
             float* __restrict__ out) {
    int i = blockIdx.x * 256 + threadIdx.x;   // f4 index
    int e0 = i * 4;
    int row = e0 >> 10;
    int h = (e0 & 1023) >> 6;
    float inv = 1.f / (la[h * LQ + row] + lb[h * LQ + row]);
    f4v a = *(const f4v*)(Oa + e0);
    f4v b = *(const f4v*)(Ob + e0);
    f4v o = (a + b) * inv;
    *(f4v*)(out + e0) = o;
}

// ---------------------------------------------------------------------------
extern "C" void kernel_launch(void* const* d_in, const int* in_sizes, int n_in,
                              void* d_out, int out_size, void* d_ws, size_t ws_size,
                              hipStream_t stream) {
    const float* w  = (const float*)d_in[0];
    const float* Wq = (const float*)d_in[1];
    const float* Wk = (const float*)d_in[2];
    const float* Wv = (const float*)d_in[3];
    const float* Wr = (const float*)d_in[4];
    const float* ub = (const float*)d_in[5];
    const float* vb = (const float*)d_in[6];
    float* out = (float*)d_out;

    const size_t U = 1048576;  // 1M shorts
    unsigned short* ws = (unsigned short*)d_ws;
    unsigned short* wbf = ws;            // 2U
    unsigned short* Wqb = ws + 2 * U;
    unsigned short* Wkb = ws + 3 * U;
    unsigned short* Wvb = ws + 4 * U;
    unsigned short* Wrb = ws + 5 * U;
    unsigned short* qb  = ws + 6 * U;    // 2U
    unsigned short* kkb = ws + 8 * U;    // 2U
    unsigned short* vtg = ws + 10 * U;   // 2U (transposed V, [DM][LQ])
    unsigned short* rp  = ws + 12 * U;   // 4U (LR*DM)
    unsigned short* r   = ws + 16 * U;   // 4U

    // overlays (dead regions during attn):
    float* Oa = (float*)(ws + 16 * U);          // over r
    float* Ob = (float*)(ws);                   // over wbf..Wkb
    float* la = (float*)(ws + 4 * U);           // over Wvb
    float* lb = la + NH * LQ;

    dim3 blk(256);
    hipLaunchKernelGGL(cast_all, dim3(3072), blk, 0, stream, w, Wq, Wk, Wv, Wr, wbf);
    hipLaunchKernelGGL(r_kernel, dim3(8190), blk, 0, stream, r);
    hipLaunchKernelGGL(proj_gemm, dim3(32, 24), blk, 0, stream,
                       wbf, Wqb, Wkb, Wvb, qb, kkb, vtg, LQ);
    hipLaunchKernelGGL(proj_gemm, dim3(64, 8), blk, 0, stream,
                       r, Wrb, Wrb, Wrb, rp, rp, rp, LR);
    hipLaunchKernelGGL(attn_mfma, dim3(1024), blk, 0, stream,
                       qb, kkb, vtg, rp, ub, vb, Oa, Ob, la, lb);
    hipLaunchKernelGGL(combine, dim3(2048), blk, 0, stream, Oa, Ob, la, lb, out);
}